// Round 4
// baseline (126.048 us; speedup 1.0000x reference)
//
#include <hip/hip_runtime.h>
#include <math.h>

// FC-CapsNet routing: u[128,1152,8], W[1152,32,8,16], b[1152,32] -> v[128,32,16]
// R4: lane layout change in caps_main: lane = (s=lane>>5, j=lane&31); each
// lane owns one parent capsule j and ALL 16 m for 2 batches. |u_hat|^2 is
// in-lane (no xor1) and the j-softmax reduce uses masks 1..16 within each
// s-half: 10 shuffles per t instead of 24. W LDS reads: s-halves read the
// same addresses -> LDS broadcast (free), unique bytes unchanged.
// NOTE (profiling): dur_us includes a fixed ~50us harness cost (256MiB d_ws
// 0xAA poison fill ~45us + d_in restore) visible as fillBufferAligned rows.

#define NB 128
#define NI 1152
#define NJ 32
#define DM 16
#define JMSZ 512            // NJ*DM

// ---------------- LDS W staging (XOR-swizzled, double-buffered) --------
// Layout [j][n][m] f32 (16KB); rows 512B; byte ^= ((j&7)<<4) spreads the
// stride-512B j-column reads across banks (proven R1/R3).
__device__ __forceinline__ float4 ldsW(const float* base, int j, int byteInRow) {
  int byte = (j << 9) + byteInRow;
  byte ^= ((j & 7) << 4);
  return *(const float4*)((const char*)base + byte);
}

template <int TPB_>
__device__ __forceinline__ void stageW(float* dst, const float* src, int tid) {
#pragma unroll
  for (int q = 0; q < 1024 / TPB_; ++q) {      // 1024 float4 = 16KB
    int o = (tid + q * TPB_) << 4;
    int so = o ^ (((o >> 9) & 7) << 4);
    *(float4*)((char*)dst + so) = *(const float4*)((const char*)src + o);
  }
}

template <int TPB_, int IC_, bool ATOMIC>
__global__ __launch_bounds__(TPB_, 4) void caps_main(
    const float* __restrict__ u, const float* __restrict__ W,
    const float* __restrict__ bias, float* __restrict__ out, int nchunk) {
  __shared__ __align__(16) float wl[2][4096];
  constexpr int BPB_ = (TPB_ / 64) * 4;        // 4 batches per wave

  const int chunk = blockIdx.x;
  const int bg = blockIdx.y;
  const int tid = threadIdx.x;
  const int wid = tid >> 6;
  const int lane = tid & 63;
  const int j = lane & 31;                     // parent capsule 0..31
  const int s = lane >> 5;                     // batch-slot half
  const int b0 = __builtin_amdgcn_readfirstlane(bg * BPB_ + wid * 4);
  const int bA = b0 + s * 2;                   // this lane's first batch
  const int i0 = chunk * IC_;

  stageW<TPB_>(wl[0], W + (size_t)i0 * 4096, tid);

  float acc[2][16];
#pragma unroll
  for (int sb = 0; sb < 2; ++sb)
#pragma unroll
    for (int m = 0; m < 16; ++m) acc[sb][m] = 0.f;

  for (int t = 0; t < IC_; ++t) {
    const int i = i0 + t;
    __syncthreads();  // wl[t&1] staged; all waves done reading wl[(t+1)&1]
    if (t + 1 < IC_) stageW<TPB_>(wl[(t + 1) & 1], W + (size_t)(i + 1) * 4096, tid);
    const float* wb = wl[t & 1];

    float un[2][8];
#pragma unroll
    for (int sb = 0; sb < 2; ++sb) {
      const float* up = u + ((size_t)(bA + sb) * NI + i) * 8;
      float4 a0 = *(const float4*)up;
      float4 a1 = *(const float4*)(up + 4);
      un[sb][0] = a0.x; un[sb][1] = a0.y; un[sb][2] = a0.z; un[sb][3] = a0.w;
      un[sb][4] = a1.x; un[sb][5] = a1.y; un[sb][6] = a1.z; un[sb][7] = a1.w;
    }
    const float bj = bias[(size_t)i * NJ + j];

    float uh[2][16];
#pragma unroll
    for (int sb = 0; sb < 2; ++sb)
#pragma unroll
      for (int m = 0; m < 16; ++m) uh[sb][m] = 0.f;

#pragma unroll
    for (int n = 0; n < 8; ++n) {
      const int rb = n * 64;
      float4 w0 = ldsW(wb, j, rb);
      float4 w1 = ldsW(wb, j, rb + 16);
      float4 w2 = ldsW(wb, j, rb + 32);
      float4 w3 = ldsW(wb, j, rb + 48);
#pragma unroll
      for (int sb = 0; sb < 2; ++sb) {
        const float uv = un[sb][n];
        uh[sb][0]  = fmaf(uv, w0.x, uh[sb][0]);
        uh[sb][1]  = fmaf(uv, w0.y, uh[sb][1]);
        uh[sb][2]  = fmaf(uv, w0.z, uh[sb][2]);
        uh[sb][3]  = fmaf(uv, w0.w, uh[sb][3]);
        uh[sb][4]  = fmaf(uv, w1.x, uh[sb][4]);
        uh[sb][5]  = fmaf(uv, w1.y, uh[sb][5]);
        uh[sb][6]  = fmaf(uv, w1.z, uh[sb][6]);
        uh[sb][7]  = fmaf(uv, w1.w, uh[sb][7]);
        uh[sb][8]  = fmaf(uv, w2.x, uh[sb][8]);
        uh[sb][9]  = fmaf(uv, w2.y, uh[sb][9]);
        uh[sb][10] = fmaf(uv, w2.z, uh[sb][10]);
        uh[sb][11] = fmaf(uv, w2.w, uh[sb][11]);
        uh[sb][12] = fmaf(uv, w3.x, uh[sb][12]);
        uh[sb][13] = fmaf(uv, w3.y, uh[sb][13]);
        uh[sb][14] = fmaf(uv, w3.z, uh[sb][14]);
        uh[sb][15] = fmaf(uv, w3.w, uh[sb][15]);
      }
    }

    // agreement (in-lane over all 16 m) + MAX-FREE softmax over j:
    // j = lane&31, so xor masks 1..16 reduce over j within each s-half.
#pragma unroll
    for (int sb = 0; sb < 2; ++sb) {
      float sq = uh[sb][0] * uh[sb][0];
#pragma unroll
      for (int m = 1; m < 16; ++m) sq = fmaf(uh[sb][m], uh[sb][m], sq);
      const float e = __expf(sq * 0.25f);      // a = sq/sqrt(16); bounded
      float es = e;
      es += __shfl_xor(es, 1);
      es += __shfl_xor(es, 2);
      es += __shfl_xor(es, 4);
      es += __shfl_xor(es, 8);
      es += __shfl_xor(es, 16);                // sum over all 32 j
      const float c = e * __builtin_amdgcn_rcpf(es) + bj;
#pragma unroll
      for (int m = 0; m < 16; ++m) acc[sb][m] = fmaf(c, uh[sb][m], acc[sb][m]);
    }
  }

#pragma unroll
  for (int sb = 0; sb < 2; ++sb) {
    if (ATOMIC) {
      float* p = out + (size_t)(bA + sb) * JMSZ + j * DM;
#pragma unroll
      for (int m = 0; m < 16; ++m) atomicAdd(p + m, acc[sb][m]);
    } else {
      float* p = out + ((size_t)(bA + sb) * nchunk + chunk) * JMSZ + j * DM;
      *(float4*)(p + 0)  = make_float4(acc[sb][0],  acc[sb][1],  acc[sb][2],  acc[sb][3]);
      *(float4*)(p + 4)  = make_float4(acc[sb][4],  acc[sb][5],  acc[sb][6],  acc[sb][7]);
      *(float4*)(p + 8)  = make_float4(acc[sb][8],  acc[sb][9],  acc[sb][10], acc[sb][11]);
      *(float4*)(p + 12) = make_float4(acc[sb][12], acc[sb][13], acc[sb][14], acc[sb][15]);
    }
  }
}

// Reduce chunk partials + squash (proven R3). 4 threads per output element
// (q = gid&3, each sums NSUM/4 chunks); q-combine and m-norm via __shfl_xor.
template <int NSUM>
__global__ __launch_bounds__(256) void caps_fin(const float* __restrict__ part,
                                                float* __restrict__ v) {
  const int gid = blockIdx.x * 256 + threadIdx.x;
  const int o = gid >> 2;                      // output element b*512+j*16+m
  const int q = gid & 3;
  float s;
  if constexpr (NSUM == 1) {
    s = part[o];                               // q-lanes read same value
  } else {
    constexpr int QC = NSUM / 4;
    const int b = o >> 9;
    const int jm = o & 511;
    const float* p = part + (size_t)b * NSUM * JMSZ + (size_t)(q * QC) * JMSZ + jm;
    s = 0.f;
#pragma unroll
    for (int cc = 0; cc < QC; ++cc) s += p[(size_t)cc * JMSZ];
    s += __shfl_xor(s, 1);                     // combine q
    s += __shfl_xor(s, 2);
  }
  float sq = s * s;                            // s uniform in lane bits 0,1
  sq += __shfl_xor(sq, 4);                     // sum over m = lane bits 2-5
  sq += __shfl_xor(sq, 8);
  sq += __shfl_xor(sq, 16);
  sq += __shfl_xor(sq, 32);
  const float nrm = sqrtf(sq);
  const float f = (sq / (1.0f + sq)) / (nrm + 1e-20f);
  if (q == 0) v[o] = f * s;
}

extern "C" void kernel_launch(void* const* d_in, const int* in_sizes, int n_in,
                              void* d_out, int out_size, void* d_ws, size_t ws_size,
                              hipStream_t stream) {
  const float* u = (const float*)d_in[0];
  const float* W = (const float*)d_in[1];
  const float* bias = (const float*)d_in[2];
  float* out = (float*)d_out;

  const size_t P128 = (size_t)NB * 128 * JMSZ * sizeof(float);  // 32 MB
  const size_t P64 = (size_t)NB * 64 * JMSZ * sizeof(float);    // 16 MB
  const int finGrid = (NB * JMSZ * 4) / 256;                    // 1024

  if (ws_size >= P128) {
    // 1024 blocks of 256 thr -> 4 blocks/CU, 4 waves/SIMD
    float* part = (float*)d_ws;
    caps_main<256, 9, false><<<dim3(128, NB / 16), 256, 0, stream>>>(u, W, bias, part, 128);
    caps_fin<128><<<finGrid, 256, 0, stream>>>(part, out);
  } else if (ws_size >= P64) {
    float* part = (float*)d_ws;
    caps_main<256, 18, false><<<dim3(64, NB / 16), 256, 0, stream>>>(u, W, bias, part, 64);
    caps_fin<64><<<finGrid, 256, 0, stream>>>(part, out);
  } else {
    float* sbuf = (float*)d_ws;
    hipMemsetAsync(sbuf, 0, (size_t)NB * JMSZ * sizeof(float), stream);
    caps_main<256, 18, true><<<dim3(64, NB / 16), 256, 0, stream>>>(u, W, bias, sbuf, 64);
    caps_fin<1><<<finGrid, 256, 0, stream>>>(sbuf, out);
  }
}

// Round 5
// 112.879 us; speedup vs baseline: 1.1167x; 1.1167x over previous
//
#include <hip/hip_runtime.h>
#include <math.h>

// FC-CapsNet routing: u[128,1152,8], W[1152,32,8,16], b[1152,32] -> v[128,32,16]
// R5: LDS-pipe-bound fix. (1) revert to proven R3 lane layout (j=lane>>1,
// h=lane&1; each lane reads only its m-octet: 16 b128 reads/t). (2) BB=8
// batches/wave halves LDS read+write cost per batch. (3) T14 async-STAGE:
// issue next W-tile global loads before compute, ds_write after (single
// barrier/iter, double-buffered LDS).
// NOTE (profiling): dur_us includes fixed ~50us harness cost (256MiB d_ws
// 0xAA poison fill ~45us + d_in restore) visible as fillBufferAligned rows.

#define NB 128
#define NI 1152
#define NJ 32
#define DM 16
#define JMSZ 512            // NJ*DM
#define BB 8                // batches register-blocked per wave

// ---------------- LDS W tile (XOR-swizzled, double-buffered) -----------
// Layout [j][n][m] f32 (16KB); rows 512B; byte ^= ((j&7)<<4) spreads the
// stride-512B j-column reads across banks (proven R1/R3).
__device__ __forceinline__ float4 ldsW(const float* base, int j, int byteInRow) {
  int byte = (j << 9) + byteInRow;
  byte ^= ((j & 7) << 4);
  return *(const float4*)((const char*)base + byte);
}

template <int TPB_>
__device__ __forceinline__ void loadW(float4* r, const float* src, int tid) {
#pragma unroll
  for (int q = 0; q < 1024 / TPB_; ++q)       // 1024 float4 = 16KB
    r[q] = *(const float4*)(src + 4 * (tid + q * TPB_));
}

template <int TPB_>
__device__ __forceinline__ void writeW(float* dst, const float4* r, int tid) {
#pragma unroll
  for (int q = 0; q < 1024 / TPB_; ++q) {
    int o = (tid + q * TPB_) << 4;
    int so = o ^ (((o >> 9) & 7) << 4);       // same involution as reader
    *(float4*)((char*)dst + so) = r[q];
  }
}

template <int TPB_, int IC_, bool ATOMIC>
__global__ __launch_bounds__(TPB_, 2) void caps_main(
    const float* __restrict__ u, const float* __restrict__ W,
    const float* __restrict__ bias, float* __restrict__ out, int nchunk) {
  __shared__ __align__(16) float wl[2][4096];
  constexpr int BPB_ = (TPB_ / 64) * BB;      // 32 batches per block

  const int chunk = blockIdx.x;
  const int bg = blockIdx.y;
  const int tid = threadIdx.x;
  const int wid = tid >> 6;
  const int lane = tid & 63;
  const int j = lane >> 1;                    // parent capsule 0..31
  const int h = lane & 1;                     // m-octet
  const int b0 = __builtin_amdgcn_readfirstlane(bg * BPB_ + wid * BB);
  const int i0 = chunk * IC_;

  float4 stg[1024 / TPB_];
  loadW<TPB_>(stg, W + (size_t)i0 * 4096, tid);

  float acc[BB][8];
#pragma unroll
  for (int bb = 0; bb < BB; ++bb)
#pragma unroll
    for (int k = 0; k < 8; ++k) acc[bb][k] = 0.f;

  writeW<TPB_>(wl[0], stg, tid);
  __syncthreads();

  for (int t = 0; t < IC_; ++t) {
    const int i = i0 + t;
    // T14: issue next-tile global loads now; wait+write after compute.
    if (t + 1 < IC_) loadW<TPB_>(stg, W + (size_t)(i + 1) * 4096, tid);
    const float* wb = wl[t & 1];

    float un[BB][8];                          // wave-uniform -> scalar loads
#pragma unroll
    for (int bb = 0; bb < BB; ++bb) {
      const float* up = u + ((size_t)(b0 + bb) * NI + i) * 8;
      float4 a0 = *(const float4*)up;
      float4 a1 = *(const float4*)(up + 4);
      un[bb][0] = a0.x; un[bb][1] = a0.y; un[bb][2] = a0.z; un[bb][3] = a0.w;
      un[bb][4] = a1.x; un[bb][5] = a1.y; un[bb][6] = a1.z; un[bb][7] = a1.w;
    }
    const float bj = bias[(size_t)i * NJ + j];

    float uh[BB][8];
#pragma unroll
    for (int bb = 0; bb < BB; ++bb)
#pragma unroll
      for (int k = 0; k < 8; ++k) uh[bb][k] = 0.f;

#pragma unroll
    for (int n = 0; n < 8; ++n) {
      const int rb = n * 64 + h * 32;
      float4 w0 = ldsW(wb, j, rb);
      float4 w1 = ldsW(wb, j, rb + 16);
#pragma unroll
      for (int bb = 0; bb < BB; ++bb) {
        const float uv = un[bb][n];
        uh[bb][0] = fmaf(uv, w0.x, uh[bb][0]);
        uh[bb][1] = fmaf(uv, w0.y, uh[bb][1]);
        uh[bb][2] = fmaf(uv, w0.z, uh[bb][2]);
        uh[bb][3] = fmaf(uv, w0.w, uh[bb][3]);
        uh[bb][4] = fmaf(uv, w1.x, uh[bb][4]);
        uh[bb][5] = fmaf(uv, w1.y, uh[bb][5]);
        uh[bb][6] = fmaf(uv, w1.z, uh[bb][6]);
        uh[bb][7] = fmaf(uv, w1.w, uh[bb][7]);
      }
    }

    // agreement + MAX-FREE softmax over j (a = |uh|^2/4 bounded; f32-safe)
    // lane = 2j+h: xor1 combines octets; xor2..32 sum over the 32 j.
#pragma unroll
    for (int bb = 0; bb < BB; ++bb) {
      float s2 = uh[bb][0] * uh[bb][0] + uh[bb][1] * uh[bb][1] +
                 uh[bb][2] * uh[bb][2] + uh[bb][3] * uh[bb][3] +
                 uh[bb][4] * uh[bb][4] + uh[bb][5] * uh[bb][5] +
                 uh[bb][6] * uh[bb][6] + uh[bb][7] * uh[bb][7];
      s2 += __shfl_xor(s2, 1);                // full |u_hat|^2 (both octets)
      const float e = __expf(s2 * 0.25f);     // a = s2/sqrt(16); no max
      float es = e;
      es += __shfl_xor(es, 2);
      es += __shfl_xor(es, 4);
      es += __shfl_xor(es, 8);
      es += __shfl_xor(es, 16);
      es += __shfl_xor(es, 32);               // sum over all 32 j
      const float c = e * __builtin_amdgcn_rcpf(es) + bj;
#pragma unroll
      for (int k = 0; k < 8; ++k) acc[bb][k] = fmaf(c, uh[bb][k], acc[bb][k]);
    }

    // T14 tail: keep compute above the staging write (don't let the
    // scheduler hoist the vmcnt wait over the FMA block).
    __builtin_amdgcn_sched_barrier(0);
    if (t + 1 < IC_) writeW<TPB_>(wl[(t + 1) & 1], stg, tid);
    __syncthreads();
  }

#pragma unroll
  for (int bb = 0; bb < BB; ++bb) {
    if (ATOMIC) {
      float* p = out + (size_t)(b0 + bb) * JMSZ + j * DM + h * 8;
#pragma unroll
      for (int k = 0; k < 8; ++k) atomicAdd(p + k, acc[bb][k]);
    } else {
      float* p = out + ((size_t)(b0 + bb) * nchunk + chunk) * JMSZ + j * DM + h * 8;
      *(float4*)p = make_float4(acc[bb][0], acc[bb][1], acc[bb][2], acc[bb][3]);
      *(float4*)(p + 4) = make_float4(acc[bb][4], acc[bb][5], acc[bb][6], acc[bb][7]);
    }
  }
}

// Reduce chunk partials + squash (proven R3). 4 threads per output element
// (q = gid&3, each sums NSUM/4 chunks); q-combine and m-norm via __shfl_xor.
template <int NSUM>
__global__ __launch_bounds__(256) void caps_fin(const float* __restrict__ part,
                                                float* __restrict__ v) {
  const int gid = blockIdx.x * 256 + threadIdx.x;
  const int o = gid >> 2;                     // output element b*512+j*16+m
  const int q = gid & 3;
  float s;
  if constexpr (NSUM == 1) {
    s = part[o];                              // q-lanes read same value
  } else {
    constexpr int QC = NSUM / 4;
    const int b = o >> 9;
    const int jm = o & 511;
    const float* p = part + (size_t)b * NSUM * JMSZ + (size_t)(q * QC) * JMSZ + jm;
    s = 0.f;
#pragma unroll
    for (int cc = 0; cc < QC; ++cc) s += p[(size_t)cc * JMSZ];
    s += __shfl_xor(s, 1);                    // combine q
    s += __shfl_xor(s, 2);
  }
  float sq = s * s;                           // s uniform in lane bits 0,1
  sq += __shfl_xor(sq, 4);                    // sum over m = lane bits 2-5
  sq += __shfl_xor(sq, 8);
  sq += __shfl_xor(sq, 16);
  sq += __shfl_xor(sq, 32);
  const float nrm = sqrtf(sq);
  const float f = (sq / (1.0f + sq)) / (nrm + 1e-20f);
  if (q == 0) v[o] = f * s;
}

extern "C" void kernel_launch(void* const* d_in, const int* in_sizes, int n_in,
                              void* d_out, int out_size, void* d_ws, size_t ws_size,
                              hipStream_t stream) {
  const float* u = (const float*)d_in[0];
  const float* W = (const float*)d_in[1];
  const float* bias = (const float*)d_in[2];
  float* out = (float*)d_out;

  const size_t P128 = (size_t)NB * 128 * JMSZ * sizeof(float);  // 32 MB
  const size_t P64 = (size_t)NB * 64 * JMSZ * sizeof(float);    // 16 MB
  const int finGrid = (NB * JMSZ * 4) / 256;                    // 1024

  if (ws_size >= P128) {
    // 512 blocks of 256 thr (BB=8) -> 2 blocks/CU
    float* part = (float*)d_ws;
    caps_main<256, 9, false><<<dim3(128, NB / 32), 256, 0, stream>>>(u, W, bias, part, 128);
    caps_fin<128><<<finGrid, 256, 0, stream>>>(part, out);
  } else if (ws_size >= P64) {
    float* part = (float*)d_ws;
    caps_main<256, 18, false><<<dim3(64, NB / 32), 256, 0, stream>>>(u, W, bias, part, 64);
    caps_fin<64><<<finGrid, 256, 0, stream>>>(part, out);
  } else {
    float* sbuf = (float*)d_ws;
    hipMemsetAsync(sbuf, 0, (size_t)NB * JMSZ * sizeof(float), stream);
    caps_main<256, 18, true><<<dim3(64, NB / 32), 256, 0, stream>>>(u, W, bias, sbuf, 64);
    caps_fin<1><<<finGrid, 256, 0, stream>>>(sbuf, out);
  }
}